// Round 2
// baseline (416.588 us; speedup 1.0000x reference)
//
#include <hip/hip_runtime.h>
#include <cstdint>
#include <cmath>

typedef __attribute__((ext_vector_type(4))) float f32x4;
typedef __attribute__((ext_vector_type(8))) short s16x8;

#define LOG2E 1.4426950408889634f

__device__ __forceinline__ unsigned short f2bf(float f) {
    unsigned int u = __float_as_uint(f);
    u += 0x7FFFu + ((u >> 16) & 1u);   // round-to-nearest-even
    return (unsigned short)(u >> 16);
}
__device__ __forceinline__ float bf2f(unsigned short s) {
    return __uint_as_float(((unsigned int)s) << 16);
}

// async global->LDS, 16B per lane. LDS dest is wave-uniform base + lane*16.
__device__ __forceinline__ void async_copy16(const void* g, void* l) {
    __builtin_amdgcn_global_load_lds(
        (const __attribute__((address_space(1))) unsigned int*)(uintptr_t)g,
        (__attribute__((address_space(3))) unsigned int*)(uintptr_t)l,
        16, 0, 0);
}

// ---------------- fp32 -> bf16 cast ----------------
__global__ __launch_bounds__(256) void cast_bf16_kernel(const float* __restrict__ in,
                                                        unsigned short* __restrict__ out,
                                                        int n4) {
    int i = blockIdx.x * 256 + threadIdx.x;
    if (i < n4) {
        float4 v = ((const float4*)in)[i];
        ushort4 o;
        o.x = f2bf(v.x); o.y = f2bf(v.y); o.z = f2bf(v.z); o.w = f2bf(v.w);
        ((ushort4*)out)[i] = o;
    }
}

// ---------------- GEMM (128x128 2-phase) — kept for the output projection ----------------
template <bool BF16_OUT>
__global__ __launch_bounds__(256) void gemm_bt(const unsigned short* __restrict__ A,
                                               const unsigned short* __restrict__ B,
                                               const float* __restrict__ bias,
                                               void* __restrict__ Cout,
                                               int M, int N, int K) {
    __shared__ unsigned short As[128 * 64];   // 16 KB
    __shared__ unsigned short Bs[128 * 64];   // 16 KB
    const int tid  = threadIdx.x;
    const int lane = tid & 63;
    const int wv   = tid >> 6;
    const int m0 = blockIdx.y * 128;
    const int n0 = blockIdx.x * 128;
    const int w_row = (wv >> 1) * 64;
    const int w_col = (wv & 1) * 64;
    const int fr = lane & 15;
    const int fg = lane >> 4;
    const int srow = lane >> 3;
    const int scol = ((lane & 7) ^ srow) * 8;
    const int rofs0 = ((fg ^ (fr & 7))) * 8;
    const int rofs1 = rofs0 ^ 32;

    f32x4 acc[4][4];
    const f32x4 zf = {0.f, 0.f, 0.f, 0.f};
    for (int r = 0; r < 4; ++r)
        for (int c = 0; c < 4; ++c) acc[r][c] = zf;

    const unsigned short* gA = A + (size_t)(m0 + wv * 32 + srow) * K + scol;
    const unsigned short* gB = B + (size_t)(n0 + wv * 32 + srow) * K + scol;

    for (int k0 = 0; k0 < K; k0 += 64) {
        for (int i = 0; i < 4; ++i)
            async_copy16(gA + (size_t)i * 8 * K + k0, &As[(wv * 32 + i * 8) * 64]);
        for (int i = 0; i < 4; ++i)
            async_copy16(gB + (size_t)i * 8 * K + k0, &Bs[(wv * 32 + i * 8) * 64]);
        __syncthreads();
        {
            s16x8 af[4], bf[4];
            for (int r = 0; r < 4; ++r)
                af[r] = *(const s16x8*)&As[(w_row + r * 16 + fr) * 64 + rofs0];
            for (int c = 0; c < 4; ++c)
                bf[c] = *(const s16x8*)&Bs[(w_col + c * 16 + fr) * 64 + rofs0];
            for (int r = 0; r < 4; ++r)
                for (int c = 0; c < 4; ++c)
                    acc[r][c] = __builtin_amdgcn_mfma_f32_16x16x32_bf16(af[r], bf[c], acc[r][c], 0, 0, 0);
        }
        {
            s16x8 af[4], bf[4];
            for (int r = 0; r < 4; ++r)
                af[r] = *(const s16x8*)&As[(w_row + r * 16 + fr) * 64 + rofs1];
            for (int c = 0; c < 4; ++c)
                bf[c] = *(const s16x8*)&Bs[(w_col + c * 16 + fr) * 64 + rofs1];
            for (int r = 0; r < 4; ++r)
                for (int c = 0; c < 4; ++c)
                    acc[r][c] = __builtin_amdgcn_mfma_f32_16x16x32_bf16(af[r], bf[c], acc[r][c], 0, 0, 0);
        }
        __syncthreads();
    }

    const int rb = (lane >> 4) * 4;
    for (int c = 0; c < 4; ++c) {
        int col = n0 + w_col + c * 16 + fr;
        float bv = bias[col];
        for (int r = 0; r < 4; ++r) {
            int row = m0 + w_row + r * 16 + rb;
            for (int q = 0; q < 4; ++q) {
                float v = acc[r][c][q] + bv;
                if constexpr (BF16_OUT)
                    ((unsigned short*)Cout)[(size_t)(row + q) * N + col] = f2bf(v);
                else
                    ((float*)Cout)[(size_t)(row + q) * N + col] = v;
            }
        }
    }
}

// ---------------- GEMM 256x256, BK=64, 8 waves, 8-phase counted-vmcnt schedule ----------------
// Staging half-tile sets match read phases exactly:
//   A-S0 = rows [0,64)u[128,192)   (read ph1 by wr=0/1)   A-S1 = rows [64,128)u[192,256) (ph3)
//   B-S0 = rows {wc*64+[0,32)}     (read ph1)              B-S1 = rows {wc*64+[32,64)}   (ph2)
// Issue in group(t): ph1: A-S1(t+1)->buf^1; ph2: A-S0(t+2); ph3: B-S0(t+2); ph4: B-S1(t+2)
// vmcnt(6) once per K-tile at ph4 -> tile t+1 fully resident entering group(t+1).

#define BAR()   __builtin_amdgcn_s_barrier()
#define LGKM0() asm volatile("s_waitcnt lgkmcnt(0)" ::: "memory")
#define VMW(N)  asm volatile("s_waitcnt vmcnt(" #N ")" ::: "memory")

#define STAGE2(gXb, XsBuf, rb, kk) \
    async_copy16(gXb + (size_t)(rb) * K + (kk), (void*)&XsBuf[(rb) * 64])

#define ST_AS0(b, kk) { STAGE2(gAb, As[b], rbA_0, kk);      STAGE2(gAb, As[b], rbA_1, kk); }
#define ST_AS1(b, kk) { STAGE2(gAb, As[b], rbA_0 + 64, kk); STAGE2(gAb, As[b], rbA_1 + 64, kk); }
#define ST_BS0(b, kk) { STAGE2(gBb, Bs[b], rbB_0, kk);      STAGE2(gBb, Bs[b], rbB_1, kk); }
#define ST_BS1(b, kk) { STAGE2(gBb, Bs[b], rbB_0 + 32, kk); STAGE2(gBb, Bs[b], rbB_1 + 32, kk); }

#define READ_A(b, mh) \
    _Pragma("unroll") \
    for (int mm_ = 0; mm_ < 4; ++mm_) { \
        const unsigned short* ap_ = &As[b][(wr * 128 + (mh) * 64 + mm_ * 16 + fr) * 64]; \
        Ar[mm_][0] = *(const s16x8*)(ap_ + rofs0); \
        Ar[mm_][1] = *(const s16x8*)(ap_ + rofs1); \
    }

#define READ_B(b, nh, Brg) \
    _Pragma("unroll") \
    for (int nn_ = 0; nn_ < 2; ++nn_) { \
        const unsigned short* bp_ = &Bs[b][(wc * 64 + (nh) * 32 + nn_ * 16 + fr) * 64]; \
        Brg[nn_][0] = *(const s16x8*)(bp_ + rofs0); \
        Brg[nn_][1] = *(const s16x8*)(bp_ + rofs1); \
    }

#define MFMA_Q(mh, nh, Brg) \
    _Pragma("unroll") \
    for (int mm_ = 0; mm_ < 4; ++mm_) { \
        _Pragma("unroll") \
        for (int nn_ = 0; nn_ < 2; ++nn_) { \
            acc[(mh) * 4 + mm_][(nh) * 2 + nn_] = __builtin_amdgcn_mfma_f32_16x16x32_bf16( \
                Ar[mm_][0], Brg[nn_][0], acc[(mh) * 4 + mm_][(nh) * 2 + nn_], 0, 0, 0); \
            acc[(mh) * 4 + mm_][(nh) * 2 + nn_] = __builtin_amdgcn_mfma_f32_16x16x32_bf16( \
                Ar[mm_][1], Brg[nn_][1], acc[(mh) * 4 + mm_][(nh) * 2 + nn_], 0, 0, 0); \
        } \
    }

#define GROUP(b, t) { \
    int x1_ = (t) + 1; if (x1_ >= ktiles) x1_ -= ktiles; \
    int x2_ = (t) + 2; if (x2_ >= ktiles) x2_ -= ktiles; \
    const int kn1 = x1_ << 6; \
    const int kn2 = x2_ << 6; \
    /* phase 1: read A-S0,B-S0; stage A-S1(t+1) into other buffer */ \
    READ_A(b, 0); \
    READ_B(b, 0, Br0); \
    ST_AS1((b) ^ 1, kn1); \
    BAR(); LGKM0(); \
    __builtin_amdgcn_s_setprio(1); MFMA_Q(0, 0, Br0); __builtin_amdgcn_s_setprio(0); \
    BAR(); \
    /* phase 2: read B-S1; stage A-S0(t+2) */ \
    READ_B(b, 1, Br1); \
    ST_AS0(b, kn2); \
    BAR(); LGKM0(); \
    __builtin_amdgcn_s_setprio(1); MFMA_Q(0, 1, Br1); __builtin_amdgcn_s_setprio(0); \
    BAR(); \
    /* phase 3: read A-S1; stage B-S0(t+2) */ \
    READ_A(b, 1); \
    ST_BS0(b, kn2); \
    BAR(); LGKM0(); \
    __builtin_amdgcn_s_setprio(1); MFMA_Q(1, 0, Br0); __builtin_amdgcn_s_setprio(0); \
    BAR(); \
    /* phase 4: stage B-S1(t+2); counted vmcnt — never drain to 0 */ \
    ST_BS1(b, kn2); \
    BAR(); \
    __builtin_amdgcn_s_setprio(1); MFMA_Q(1, 1, Br1); __builtin_amdgcn_s_setprio(0); \
    VMW(6); \
    BAR(); \
}

__global__ __launch_bounds__(512, 2) void gemm256_bt(const unsigned short* __restrict__ A,
                                                     const unsigned short* __restrict__ B,
                                                     const float* __restrict__ bias,
                                                     unsigned short* __restrict__ C,
                                                     int M, int N, int K) {
    __shared__ unsigned short As[2][256 * 64];   // 64 KB
    __shared__ unsigned short Bs[2][256 * 64];   // 64 KB
    const int tid  = threadIdx.x;
    const int lane = tid & 63;
    const int wv   = tid >> 6;      // 0..7
    const int wr   = wv >> 2;       // 0..1 (M-half)
    const int wc   = wv & 3;        // 0..3 (N-quarter)
    // XCD-aware chunked mapping (round-robin dispatch: xcd = bid&7, per m09/m192).
    // Each XCD owns 2 A-strips x 15 B-panels; each B-panel is shared by 2
    // lock-stepped co-XCD blocks -> B prefetch hits L2 instead of HBM.
    // Bijection: (j in [0,8)) x (local in [0,30)) -> strip in [0,8) x panel in [0,30).
    const int j     = blockIdx.x & 7;
    const int local = blockIdx.x >> 3;
    const int strip = 2 * (j & 3) + (local & 1);
    const int panel = (j >> 2) * 15 + (local >> 1);
    const int m0 = strip * 256;
    const int n0 = panel * 256;
    const int fr = lane & 15;
    const int fg = lane >> 4;
    const int rofs0 = (fg ^ (fr & 7)) * 8;
    const int rofs1 = rofs0 ^ 32;
    // staging: lane covers row (lane>>3), fetches global chunk (lane&7)^((lane>>3)&7)
    const int rlane = lane >> 3;
    const int swzc  = ((lane & 7) ^ (rlane & 7)) * 8;
    const int idx0 = wv * 2, idx1 = wv * 2 + 1;
    const int rbA_0 = idx0 * 8 + ((idx0 >= 8) ? 64 : 0);  // A-S0 row bases
    const int rbA_1 = idx1 * 8 + ((idx1 >= 8) ? 64 : 0);
    const int rbB_0 = (idx0 >> 2) * 64 + (idx0 & 3) * 8;  // B-S0 row bases
    const int rbB_1 = (idx1 >> 2) * 64 + (idx1 & 3) * 8;
    const int ktiles = K >> 6;      // 40

    const unsigned short* gAb = A + (size_t)(m0 + rlane) * K + swzc;
    const unsigned short* gBb = B + (size_t)(n0 + rlane) * K + swzc;

    f32x4 acc[8][4];
    const f32x4 zf = {0.f, 0.f, 0.f, 0.f};
#pragma unroll
    for (int i = 0; i < 8; ++i)
#pragma unroll
        for (int jj = 0; jj < 4; ++jj) acc[i][jj] = zf;

    s16x8 Ar[4][2], Br0[2][2], Br1[2][2];

    // prologue: tile0 complete + tile1 {A-S0, B-S0, B-S1}; A-S1(1) issued in group(0) ph1
    ST_AS0(0, 0); ST_AS1(0, 0); ST_BS0(0, 0); ST_BS1(0, 0);
    ST_AS0(1, 64); ST_BS0(1, 64); ST_BS1(1, 64);
    VMW(6);           // tile0's 8 loads drained; tile1's 6 may stay in flight
    BAR();

    const int nit = ktiles >> 1;
    for (int it = 0; it < nit; ++it) {
        GROUP(0, it * 2);
        GROUP(1, it * 2 + 1);
    }

    // epilogue: C/D layout col=lane&15, row=(lane>>4)*4+reg
    const int rb = (lane >> 4) * 4;
#pragma unroll
    for (int nn = 0; nn < 4; ++nn) {
        int col = n0 + wc * 64 + nn * 16 + fr;
        float bv = bias[col];
#pragma unroll
        for (int mm = 0; mm < 8; ++mm) {
            int row = m0 + wr * 128 + mm * 16 + rb;
#pragma unroll
            for (int q = 0; q < 4; ++q) {
                float v = acc[mm][nn][q] + bv;
                C[(size_t)(row + q) * N + col] = f2bf(v);
            }
        }
    }
}

// ---------------- RoPE in-place on q-half only (k handled in rope_pack_k) ----------------
__global__ __launch_bounds__(256) void rope_q_kernel(unsigned short* __restrict__ qkv) {
    int g = blockIdx.x * 256 + threadIdx.x;  // 2048*32*2 items
    int c = g & 1;            // half-chunk: pairs d0..d0+7
    int h = (g >> 1) & 31;
    int p = g >> 6;
    size_t base = (size_t)p * 7680 + h * 80 + c * 8;
    s16x8 x1v = *(const s16x8*)(qkv + base);
    s16x8 x2v = *(const s16x8*)(qkv + base + 16);
    s16x8 o1, o2;
    for (int j = 0; j < 8; ++j) {
        int dp = c * 8 + j;
        float freq = expf(-(float)dp * 0.57564627324851142f);  // ln(10000)/16
        float sn, cs;
        sincosf((float)p * freq, &sn, &cs);
        float x1 = bf2f((unsigned short)x1v[j]);
        float x2 = bf2f((unsigned short)x2v[j]);
        o1[j] = (short)f2bf(x1 * cs - x2 * sn);
        o2[j] = (short)f2bf(x1 * sn + x2 * cs);
    }
    *(s16x8*)(qkv + base)      = o1;
    *(s16x8*)(qkv + base + 16) = o2;
}

// ---------------- fused k-RoPE + pack: qkv k-half -> Kp[h][key][96] ----------------
__global__ __launch_bounds__(256) void rope_pack_k_kernel(const unsigned short* __restrict__ qkv,
                                                          unsigned short* __restrict__ Kp) {
    int g = blockIdx.x * 256 + threadIdx.x;  // 2048*32*12
    int c   = g % 12;
    int h   = (g / 12) & 31;
    int pos = g / 384;
    int d0 = c * 8;
    const unsigned short* kb = qkv + (size_t)pos * 7680 + 2560 + h * 80;
    s16x8 v = {0, 0, 0, 0, 0, 0, 0, 0};
    if (c >= 4) {
        if (d0 < 80) v = *(const s16x8*)(kb + d0);
    } else if (c < 2) {          // x1 side: out = x1*cos - x2*sin
        s16x8 x1v = *(const s16x8*)(kb + d0);
        s16x8 x2v = *(const s16x8*)(kb + d0 + 16);
        for (int j = 0; j < 8; ++j) {
            int dp = d0 + j;
            float freq = expf(-(float)dp * 0.57564627324851142f);
            float sn, cs;
            sincosf((float)pos * freq, &sn, &cs);
            v[j] = (short)f2bf(bf2f((unsigned short)x1v[j]) * cs -
                               bf2f((unsigned short)x2v[j]) * sn);
        }
    } else {                     // x2 side: out = x1*sin + x2*cos
        s16x8 x1v = *(const s16x8*)(kb + d0 - 16);
        s16x8 x2v = *(const s16x8*)(kb + d0);
        for (int j = 0; j < 8; ++j) {
            int dp = d0 - 16 + j;
            float freq = expf(-(float)dp * 0.57564627324851142f);
            float sn, cs;
            sincosf((float)pos * freq, &sn, &cs);
            v[j] = (short)f2bf(bf2f((unsigned short)x1v[j]) * sn +
                               bf2f((unsigned short)x2v[j]) * cs);
        }
    }
    *(s16x8*)(Kp + ((size_t)h * 2048 + pos) * 96 + d0) = v;
}

// ---------------- pack V^T tiled: qkv v-half -> Vp[h][kblk16][80][16] ----------------
__global__ __launch_bounds__(256) void pack_v_kernel(const unsigned short* __restrict__ qkv,
                                                     unsigned short* __restrict__ Vp) {
    int h  = blockIdx.x & 31;
    int g64 = blockIdx.x >> 5;           // 0..31
    int k0 = g64 * 64;
    int tid = threadIdx.x;
    for (int ci = tid; ci < 320; ci += 256) {   // (kbl 0..3) x (d 0..79)
        int d   = ci % 80;
        int kbl = ci / 80;
        unsigned short tmp[16];
        for (int j = 0; j < 16; ++j)
            tmp[j] = qkv[(size_t)(k0 + kbl * 16 + j) * 7680 + 5120 + h * 80 + d];
        unsigned short* dst = Vp + ((size_t)h * 128 + g64 * 4 + kbl) * 1280 + d * 16;
        *(s16x8*)dst       = *(const s16x8*)&tmp[0];
        *(s16x8*)(dst + 8) = *(const s16x8*)&tmp[8];
    }
}

// ---------------- flash attention v3: fixed-max softmax, split-K, pair-balanced ----------------
__global__ __launch_bounds__(256) void flash3_kernel(const unsigned short* __restrict__ qkv,
                                                     const unsigned short* __restrict__ Kp,
                                                     const unsigned short* __restrict__ Vp,
                                                     unsigned short* __restrict__ attn) {
    __shared__ unsigned short Pt[4][640];      // per-wave 16x40 P tile
    __shared__ float parts[2][16][84];         // odd-wave O partials (pitch 84)
    __shared__ float parts_l[2][16];           // odd-wave row-sum partials
    const int tid  = threadIdx.x;
    const int lane = tid & 63;
    const int wv   = tid >> 6;
    const int h = blockIdx.x & 31;
    const int p = blockIdx.x >> 5;             // 0..63
    const int s    = (wv < 2) ? p : (127 - p); // strip index (16 q rows)
    const int j    = wv & 1;                   // key-range half
    const int slot = wv >> 1;
    const int fr = lane & 15;
    const int fg = lane >> 4;
    const float k1 = 0.11180339887498949f * LOG2E;  // (1/sqrt(80)) * log2(e)
    const int sm16 = s * 16;

    const int n    = s + 1;                    // causal 16-key tiles
    const int half = (n + 1) >> 1;
    const int kstart = (j ? half : 0) * 16;
    const int kend   = (j ? n : half) * 16;

    s16x8 qf[3];
    {
        const unsigned short* qb = qkv + (size_t)(sm16 + fr) * 7680 + h * 80;
        const s16x8 zs = {0, 0, 0, 0, 0, 0, 0, 0};
        for (int sd = 0; sd < 3; ++sd) {
            int d = 32 * sd + fg * 8;
            qf[sd] = (d < 80) ? *(const s16x8*)(qb + d) : zs;
        }
    }

    f32x4 O[5];
    const f32x4 zf = {0.f, 0.f, 0.f, 0.f};
    for (int t = 0; t < 5; ++t) O[t] = zf;
    float rs[4] = {0.f, 0.f, 0.f, 0.f};

    const unsigned short* kptr = Kp + (size_t)h * 2048 * 96 + (size_t)(kstart + fr) * 96 + fg * 8;
    const unsigned short* vptr = Vp + (size_t)h * 128 * 1280 + (size_t)(kstart >> 4) * 1280
                                 + (fg >> 1) * 1280 + fr * 16 + (fg & 1) * 8;
    unsigned short* Pw = &Pt[wv][0];

    for (int k0 = kstart; k0 < kend; k0 += 32) {
        s16x8 kb[2][3];
        for (int g = 0; g < 2; ++g)
            for (int sd = 0; sd < 3; ++sd)
                kb[g][sd] = *(const s16x8*)(kptr + g * 1536 + sd * 32);
        s16x8 vb[5];
        for (int t = 0; t < 5; ++t)
            vb[t] = *(const s16x8*)(vptr + t * 256);

        f32x4 sa[2] = {zf, zf};
        for (int g = 0; g < 2; ++g)
            for (int sd = 0; sd < 3; ++sd)
                sa[g] = __builtin_amdgcn_mfma_f32_16x16x32_bf16(qf[sd], kb[g][sd], sa[g], 0, 0, 0);

        if (k0 + 32 > sm16 || k0 + 32 > kend) {
            for (int g = 0; g < 2; ++g)
                for (int r = 0; r < 4; ++r) {
                    int key  = k0 + g * 16 + fr;
                    int qrow = sm16 + fg * 4 + r;
                    if (key > qrow || key >= kend) sa[g][r] = -1e30f;
                }
        }

        float pr[2][4];
        for (int g = 0; g < 2; ++g)
            for (int r = 0; r < 4; ++r)
                pr[g][r] = __builtin_amdgcn_exp2f(sa[g][r] * k1);
        for (int r = 0; r < 4; ++r) rs[r] += pr[0][r] + pr[1][r];
        for (int g = 0; g < 2; ++g)
            for (int r = 0; r < 4; ++r)
                Pw[(fg * 4 + r) * 40 + g * 16 + fr] =
                    (unsigned short)(__float_as_uint(pr[g][r]) >> 16);

        s16x8 pa = *(const s16x8*)(Pw + fr * 40 + fg * 8);
        for (int t = 0; t < 5; ++t)
            O[t] = __builtin_amdgcn_mfma_f32_16x16x32_bf16(pa, vb[t], O[t], 0, 0, 0);

        kptr += 3072;   // 32 keys * 96
        vptr += 2560;   // 2 blocks * 1280
    }

    for (int r = 0; r < 4; ++r) {
        float v = rs[r];
        v += __shfl_xor(v, 1);
        v += __shfl_xor(v, 2);
        v += __shfl_xor(v, 4);
        v += __shfl_xor(v, 8);
        rs[r] = v;
    }

    if (j) {
        for (int t = 0; t < 5; ++t)
            for (int r = 0; r < 4; ++r)
                parts[slot][fg * 4 + r][t * 16 + fr] = O[t][r];
        if (fr == 0)
            for (int r = 0; r < 4; ++r) parts_l[slot][fg * 4 + r] = rs[r];
    }
    __syncthreads();
    if (!j) {
        for (int r = 0; r < 4; ++r) {
            float rl = 1.0f / (rs[r] + parts_l[slot][fg * 4 + r]);
            int row = sm16 + fg * 4 + r;
            for (int t = 0; t < 5; ++t) {
                float v = (O[t][r] + parts[slot][fg * 4 + r][t * 16 + fr]) * rl;
                attn[(size_t)row * 2560 + h * 80 + t * 16 + fr] = f2bf(v);
            }
        }
    }
}

extern "C" void kernel_launch(void* const* d_in, const int* in_sizes, int n_in,
                              void* d_out, int out_size, void* d_ws, size_t ws_size,
                              hipStream_t stream) {
    const float* x    = (const float*)d_in[0];
    const float* wqkv = (const float*)d_in[1];
    const float* bqkv = (const float*)d_in[2];
    const float* outw = (const float*)d_in[3];
    const float* outb = (const float*)d_in[4];

    unsigned short* xb    = (unsigned short*)d_ws;                  // 2048*2560
    unsigned short* wqkvb = xb + (size_t)2048 * 2560;               // 7680*2560 (dead after gemm1)
    unsigned short* Kp    = wqkvb;                                  // 32*2048*96   (aliases wqkvb)
    unsigned short* Vp    = wqkvb + (size_t)32 * 2048 * 96;         // 32*128*1280  (aliases wqkvb)
    unsigned short* outwb = wqkvb + (size_t)7680 * 2560;            // 2560*2560
    unsigned short* qkvb  = outwb + (size_t)2560 * 2560;            // 2048*7680
    unsigned short* attnb = qkvb  + (size_t)2048 * 7680;            // 2048*2560
    float* out = (float*)d_out;

    cast_bf16_kernel<<<2048 * 2560 / 4 / 256, 256, 0, stream>>>(x, xb, 2048 * 2560 / 4);
    cast_bf16_kernel<<<7680 * 2560 / 4 / 256, 256, 0, stream>>>(wqkv, wqkvb, 7680 * 2560 / 4);
    cast_bf16_kernel<<<2560 * 2560 / 4 / 256, 256, 0, stream>>>(outw, outwb, 2560 * 2560 / 4);

    // qkv projection: 256x256 8-phase kernel, 240 blocks, XCD-chunked panel-sharing map
    gemm256_bt<<<240, 512, 0, stream>>>(xb, wqkvb, bqkv, qkvb, 2048, 7680, 2560);

    rope_q_kernel<<<2048 * 64 / 256, 256, 0, stream>>>(qkvb);
    rope_pack_k_kernel<<<2048 * 384 / 256, 256, 0, stream>>>(qkvb, Kp);
    pack_v_kernel<<<32 * 32, 256, 0, stream>>>(qkvb, Vp);

    flash3_kernel<<<2048, 256, 0, stream>>>(qkvb, Kp, Vp, attnb);

    gemm_bt<false><<<dim3(2560 / 128, 2048 / 128), 256, 0, stream>>>(
        attnb, outwb, outb, (void*)out, 2048, 2560, 2560);
}

// Round 3
// 414.075 us; speedup vs baseline: 1.0061x; 1.0061x over previous
//
#include <hip/hip_runtime.h>
#include <cstdint>
#include <cmath>

typedef __attribute__((ext_vector_type(4))) float f32x4;
typedef __attribute__((ext_vector_type(8))) short s16x8;

#define LOG2E 1.4426950408889634f

__device__ __forceinline__ unsigned short f2bf(float f) {
    unsigned int u = __float_as_uint(f);
    u += 0x7FFFu + ((u >> 16) & 1u);   // round-to-nearest-even
    return (unsigned short)(u >> 16);
}
__device__ __forceinline__ float bf2f(unsigned short s) {
    return __uint_as_float(((unsigned int)s) << 16);
}

// async global->LDS, 16B per lane. LDS dest is wave-uniform base + lane*16.
__device__ __forceinline__ void async_copy16(const void* g, void* l) {
    __builtin_amdgcn_global_load_lds(
        (const __attribute__((address_space(1))) unsigned int*)(uintptr_t)g,
        (__attribute__((address_space(3))) unsigned int*)(uintptr_t)l,
        16, 0, 0);
}

// ---------------- fp32 -> bf16 cast ----------------
__global__ __launch_bounds__(256) void cast_bf16_kernel(const float* __restrict__ in,
                                                        unsigned short* __restrict__ out,
                                                        int n4) {
    int i = blockIdx.x * 256 + threadIdx.x;
    if (i < n4) {
        float4 v = ((const float4*)in)[i];
        ushort4 o;
        o.x = f2bf(v.x); o.y = f2bf(v.y); o.z = f2bf(v.z); o.w = f2bf(v.w);
        ((ushort4*)out)[i] = o;
    }
}

// ---------------- GEMM (128x128 2-phase) — kept for the output projection ----------------
template <bool BF16_OUT>
__global__ __launch_bounds__(256) void gemm_bt(const unsigned short* __restrict__ A,
                                               const unsigned short* __restrict__ B,
                                               const float* __restrict__ bias,
                                               void* __restrict__ Cout,
                                               int M, int N, int K) {
    __shared__ unsigned short As[128 * 64];   // 16 KB
    __shared__ unsigned short Bs[128 * 64];   // 16 KB
    const int tid  = threadIdx.x;
    const int lane = tid & 63;
    const int wv   = tid >> 6;
    const int m0 = blockIdx.y * 128;
    const int n0 = blockIdx.x * 128;
    const int w_row = (wv >> 1) * 64;
    const int w_col = (wv & 1) * 64;
    const int fr = lane & 15;
    const int fg = lane >> 4;
    const int srow = lane >> 3;
    const int scol = ((lane & 7) ^ srow) * 8;
    const int rofs0 = ((fg ^ (fr & 7))) * 8;
    const int rofs1 = rofs0 ^ 32;

    f32x4 acc[4][4];
    const f32x4 zf = {0.f, 0.f, 0.f, 0.f};
    for (int r = 0; r < 4; ++r)
        for (int c = 0; c < 4; ++c) acc[r][c] = zf;

    const unsigned short* gA = A + (size_t)(m0 + wv * 32 + srow) * K + scol;
    const unsigned short* gB = B + (size_t)(n0 + wv * 32 + srow) * K + scol;

    for (int k0 = 0; k0 < K; k0 += 64) {
        for (int i = 0; i < 4; ++i)
            async_copy16(gA + (size_t)i * 8 * K + k0, &As[(wv * 32 + i * 8) * 64]);
        for (int i = 0; i < 4; ++i)
            async_copy16(gB + (size_t)i * 8 * K + k0, &Bs[(wv * 32 + i * 8) * 64]);
        __syncthreads();
        {
            s16x8 af[4], bf[4];
            for (int r = 0; r < 4; ++r)
                af[r] = *(const s16x8*)&As[(w_row + r * 16 + fr) * 64 + rofs0];
            for (int c = 0; c < 4; ++c)
                bf[c] = *(const s16x8*)&Bs[(w_col + c * 16 + fr) * 64 + rofs0];
            for (int r = 0; r < 4; ++r)
                for (int c = 0; c < 4; ++c)
                    acc[r][c] = __builtin_amdgcn_mfma_f32_16x16x32_bf16(af[r], bf[c], acc[r][c], 0, 0, 0);
        }
        {
            s16x8 af[4], bf[4];
            for (int r = 0; r < 4; ++r)
                af[r] = *(const s16x8*)&As[(w_row + r * 16 + fr) * 64 + rofs1];
            for (int c = 0; c < 4; ++c)
                bf[c] = *(const s16x8*)&Bs[(w_col + c * 16 + fr) * 64 + rofs1];
            for (int r = 0; r < 4; ++r)
                for (int c = 0; c < 4; ++c)
                    acc[r][c] = __builtin_amdgcn_mfma_f32_16x16x32_bf16(af[r], bf[c], acc[r][c], 0, 0, 0);
        }
        __syncthreads();
    }

    const int rb = (lane >> 4) * 4;
    for (int c = 0; c < 4; ++c) {
        int col = n0 + w_col + c * 16 + fr;
        float bv = bias[col];
        for (int r = 0; r < 4; ++r) {
            int row = m0 + w_row + r * 16 + rb;
            for (int q = 0; q < 4; ++q) {
                float v = acc[r][c][q] + bv;
                if constexpr (BF16_OUT)
                    ((unsigned short*)Cout)[(size_t)(row + q) * N + col] = f2bf(v);
                else
                    ((float*)Cout)[(size_t)(row + q) * N + col] = v;
            }
        }
    }
}

// ---------------- GEMM 256x256, BK=64, 8 waves — v3: decoupled read/MFMA pipeline ----------
// Per tile t (buf b), quadrant order Q00,Q01,Q11,Q10. Each phase:
//   {setprio(1) MFMA(regs read >=1 phase ago) setprio(0); VMW(6); ds_reads(next); stage; BAR}
// Reads: P1: B1(t) [use P2]; P2: A1(t) [use P3]; P3: none; P4: A0,B0(t+1) from buf^1 [use P1'].
// Register sharing (no extra frags): Ar holds A0 (P1,P2) then A1 (P3,P4); Br0 holds B0(t)
// (written P4(t-1), used P1&P4); Br1 holds B1(t) (written P1, used P2,P3).
// Staging (unchanged): P1: AS1(t+1)->buf^1; P2: AS0(t+2); P3: BS0(t+2); P4: BS1(t+2).
// Drain ledger (uniform VMW(6), 6-8 loads always in flight): P1 drains AS1(t) [P2's A1 read],
// P2 drains AS0(t+1) [P4's A0' read], P3 drains BS0(t+1) [P4's B0' read], P4 drains BS1(t+1)
// [P1' B1 read]. Overwrite hazards: every staged slot's old readers completed >=1 barrier
// earlier (consumer-MFMA lgkm + that phase's closing barrier). One barrier per phase.

#define BAR()   __builtin_amdgcn_s_barrier()
#define VMW(N)  asm volatile("s_waitcnt vmcnt(" #N ")" ::: "memory")

#define STAGE2(gXb, XsBuf, rb, kk) \
    async_copy16(gXb + (size_t)(rb) * K + (kk), (void*)&XsBuf[(rb) * 64])

#define ST_AS0(b, kk) { STAGE2(gAb, As[b], rbA_0, kk);      STAGE2(gAb, As[b], rbA_1, kk); }
#define ST_AS1(b, kk) { STAGE2(gAb, As[b], rbA_0 + 64, kk); STAGE2(gAb, As[b], rbA_1 + 64, kk); }
#define ST_BS0(b, kk) { STAGE2(gBb, Bs[b], rbB_0, kk);      STAGE2(gBb, Bs[b], rbB_1, kk); }
#define ST_BS1(b, kk) { STAGE2(gBb, Bs[b], rbB_0 + 32, kk); STAGE2(gBb, Bs[b], rbB_1 + 32, kk); }

#define READ_A(b, mh) \
    _Pragma("unroll") \
    for (int mm_ = 0; mm_ < 4; ++mm_) { \
        const unsigned short* ap_ = &As[b][(wr * 128 + (mh) * 64 + mm_ * 16 + fr) * 64]; \
        Ar[mm_][0] = *(const s16x8*)(ap_ + rofs0); \
        Ar[mm_][1] = *(const s16x8*)(ap_ + rofs1); \
    }

#define READ_B(b, nh, Brg) \
    _Pragma("unroll") \
    for (int nn_ = 0; nn_ < 2; ++nn_) { \
        const unsigned short* bp_ = &Bs[b][(wc * 64 + (nh) * 32 + nn_ * 16 + fr) * 64]; \
        Brg[nn_][0] = *(const s16x8*)(bp_ + rofs0); \
        Brg[nn_][1] = *(const s16x8*)(bp_ + rofs1); \
    }

#define MFMA_Q(mh, nh, Brg) \
    _Pragma("unroll") \
    for (int mm_ = 0; mm_ < 4; ++mm_) { \
        _Pragma("unroll") \
        for (int nn_ = 0; nn_ < 2; ++nn_) { \
            acc[(mh) * 4 + mm_][(nh) * 2 + nn_] = __builtin_amdgcn_mfma_f32_16x16x32_bf16( \
                Ar[mm_][0], Brg[nn_][0], acc[(mh) * 4 + mm_][(nh) * 2 + nn_], 0, 0, 0); \
            acc[(mh) * 4 + mm_][(nh) * 2 + nn_] = __builtin_amdgcn_mfma_f32_16x16x32_bf16( \
                Ar[mm_][1], Brg[nn_][1], acc[(mh) * 4 + mm_][(nh) * 2 + nn_], 0, 0, 0); \
        } \
    }

#define GROUP(b, t) { \
    int x1_ = (t) + 1; if (x1_ >= ktiles) x1_ -= ktiles; \
    int x2_ = (t) + 2; if (x2_ >= ktiles) x2_ -= ktiles; \
    const int kn1 = x1_ << 6; \
    const int kn2 = x2_ << 6; \
    /* P1: Q00 (A0 x B0, regs from P4(t-1)); read B1(t); stage AS1(t+1) */ \
    __builtin_amdgcn_s_setprio(1); MFMA_Q(0, 0, Br0); __builtin_amdgcn_s_setprio(0); \
    VMW(6); \
    READ_B(b, 1, Br1); \
    ST_AS1((b) ^ 1, kn1); \
    BAR(); \
    /* P2: Q01 (A0 x B1); read A1(t) (frees A0 after MFMA); stage AS0(t+2) */ \
    __builtin_amdgcn_s_setprio(1); MFMA_Q(0, 1, Br1); __builtin_amdgcn_s_setprio(0); \
    VMW(6); \
    READ_A(b, 1); \
    ST_AS0(b, kn2); \
    BAR(); \
    /* P3: Q11 (A1 x B1); stage BS0(t+2) */ \
    __builtin_amdgcn_s_setprio(1); MFMA_Q(1, 1, Br1); __builtin_amdgcn_s_setprio(0); \
    VMW(6); \
    ST_BS0(b, kn2); \
    BAR(); \
    /* P4: Q10 (A1 x B0); read A0,B0 of tile t+1 from buf^1; stage BS1(t+2) */ \
    __builtin_amdgcn_s_setprio(1); MFMA_Q(1, 0, Br0); __builtin_amdgcn_s_setprio(0); \
    VMW(6); \
    READ_A((b) ^ 1, 0); \
    READ_B((b) ^ 1, 0, Br0); \
    ST_BS1(b, kn2); \
    BAR(); \
}

__global__ __launch_bounds__(512, 2) void gemm256_bt(const unsigned short* __restrict__ A,
                                                     const unsigned short* __restrict__ B,
                                                     const float* __restrict__ bias,
                                                     unsigned short* __restrict__ C,
                                                     int M, int N, int K) {
    __shared__ unsigned short As[2][256 * 64];   // 64 KB
    __shared__ unsigned short Bs[2][256 * 64];   // 64 KB
    const int tid  = threadIdx.x;
    const int lane = tid & 63;
    const int wv   = tid >> 6;      // 0..7
    const int wr   = wv >> 2;       // 0..1 (M-half)
    const int wc   = wv & 3;        // 0..3 (N-quarter)
    // XCD-aware chunked mapping (round-robin dispatch: xcd = bid&7).
    // Each XCD: 2 A-strips x 15 B-panels; each B-panel shared by 2 co-XCD blocks.
    const int j     = blockIdx.x & 7;
    const int local = blockIdx.x >> 3;
    const int strip = 2 * (j & 3) + (local & 1);
    const int panel = (j >> 2) * 15 + (local >> 1);
    const int m0 = strip * 256;
    const int n0 = panel * 256;
    const int fr = lane & 15;
    const int fg = lane >> 4;
    const int rofs0 = (fg ^ (fr & 7)) * 8;
    const int rofs1 = rofs0 ^ 32;
    // staging: lane covers row (lane>>3), fetches global chunk (lane&7)^((lane>>3)&7)
    const int rlane = lane >> 3;
    const int swzc  = ((lane & 7) ^ (rlane & 7)) * 8;
    const int idx0 = wv * 2, idx1 = wv * 2 + 1;
    const int rbA_0 = idx0 * 8 + ((idx0 >= 8) ? 64 : 0);  // A-S0 row bases
    const int rbA_1 = idx1 * 8 + ((idx1 >= 8) ? 64 : 0);
    const int rbB_0 = (idx0 >> 2) * 64 + (idx0 & 3) * 8;  // B-S0 row bases
    const int rbB_1 = (idx1 >> 2) * 64 + (idx1 & 3) * 8;
    const int ktiles = K >> 6;      // 40

    const unsigned short* gAb = A + (size_t)(m0 + rlane) * K + swzc;
    const unsigned short* gBb = B + (size_t)(n0 + rlane) * K + swzc;

    f32x4 acc[8][4];
    const f32x4 zf = {0.f, 0.f, 0.f, 0.f};
#pragma unroll
    for (int i = 0; i < 8; ++i)
#pragma unroll
        for (int jj = 0; jj < 4; ++jj) acc[i][jj] = zf;

    s16x8 Ar[4][2], Br0[2][2], Br1[2][2];

    // prologue: tile0 complete + tile1 {AS0, BS0, BS1} (AS1(1) comes in P1 of GROUP 0);
    // drain tile0 (VMW(6) leaves tile1's 6 in flight); pre-read A0(t0), B0(t0).
    ST_AS0(0, 0); ST_AS1(0, 0); ST_BS0(0, 0); ST_BS1(0, 0);
    ST_AS0(1, 64); ST_BS0(1, 64); ST_BS1(1, 64);
    VMW(6);
    BAR();
    READ_A(0, 0);
    READ_B(0, 0, Br0);

    const int nit = ktiles >> 1;
    for (int it = 0; it < nit; ++it) {
        GROUP(0, it * 2);
        GROUP(1, it * 2 + 1);
    }

    // epilogue: C/D layout col=lane&15, row=(lane>>4)*4+reg
    const int rb = (lane >> 4) * 4;
#pragma unroll
    for (int nn = 0; nn < 4; ++nn) {
        int col = n0 + wc * 64 + nn * 16 + fr;
        float bv = bias[col];
#pragma unroll
        for (int mm = 0; mm < 8; ++mm) {
            int row = m0 + wr * 128 + mm * 16 + rb;
#pragma unroll
            for (int q = 0; q < 4; ++q) {
                float v = acc[mm][nn][q] + bv;
                C[(size_t)(row + q) * N + col] = f2bf(v);
            }
        }
    }
}

// ---------------- RoPE in-place on q-half only (k handled in rope_pack_k) ----------------
__global__ __launch_bounds__(256) void rope_q_kernel(unsigned short* __restrict__ qkv) {
    int g = blockIdx.x * 256 + threadIdx.x;  // 2048*32*2 items
    int c = g & 1;            // half-chunk: pairs d0..d0+7
    int h = (g >> 1) & 31;
    int p = g >> 6;
    size_t base = (size_t)p * 7680 + h * 80 + c * 8;
    s16x8 x1v = *(const s16x8*)(qkv + base);
    s16x8 x2v = *(const s16x8*)(qkv + base + 16);
    s16x8 o1, o2;
    for (int j = 0; j < 8; ++j) {
        int dp = c * 8 + j;
        float freq = expf(-(float)dp * 0.57564627324851142f);  // ln(10000)/16
        float sn, cs;
        sincosf((float)p * freq, &sn, &cs);
        float x1 = bf2f((unsigned short)x1v[j]);
        float x2 = bf2f((unsigned short)x2v[j]);
        o1[j] = (short)f2bf(x1 * cs - x2 * sn);
        o2[j] = (short)f2bf(x1 * sn + x2 * cs);
    }
    *(s16x8*)(qkv + base)      = o1;
    *(s16x8*)(qkv + base + 16) = o2;
}

// ---------------- fused k-RoPE + pack: qkv k-half -> Kp[h][key][96] ----------------
__global__ __launch_bounds__(256) void rope_pack_k_kernel(const unsigned short* __restrict__ qkv,
                                                          unsigned short* __restrict__ Kp) {
    int g = blockIdx.x * 256 + threadIdx.x;  // 2048*32*12
    int c   = g % 12;
    int h   = (g / 12) & 31;
    int pos = g / 384;
    int d0 = c * 8;
    const unsigned short* kb = qkv + (size_t)pos * 7680 + 2560 + h * 80;
    s16x8 v = {0, 0, 0, 0, 0, 0, 0, 0};
    if (c >= 4) {
        if (d0 < 80) v = *(const s16x8*)(kb + d0);
    } else if (c < 2) {          // x1 side: out = x1*cos - x2*sin
        s16x8 x1v = *(const s16x8*)(kb + d0);
        s16x8 x2v = *(const s16x8*)(kb + d0 + 16);
        for (int j = 0; j < 8; ++j) {
            int dp = d0 + j;
            float freq = expf(-(float)dp * 0.57564627324851142f);
            float sn, cs;
            sincosf((float)pos * freq, &sn, &cs);
            v[j] = (short)f2bf(bf2f((unsigned short)x1v[j]) * cs -
                               bf2f((unsigned short)x2v[j]) * sn);
        }
    } else {                     // x2 side: out = x1*sin + x2*cos
        s16x8 x1v = *(const s16x8*)(kb + d0 - 16);
        s16x8 x2v = *(const s16x8*)(kb + d0);
        for (int j = 0; j < 8; ++j) {
            int dp = d0 - 16 + j;
            float freq = expf(-(float)dp * 0.57564627324851142f);
            float sn, cs;
            sincosf((float)pos * freq, &sn, &cs);
            v[j] = (short)f2bf(bf2f((unsigned short)x1v[j]) * sn +
                               bf2f((unsigned short)x2v[j]) * cs);
        }
    }
    *(s16x8*)(Kp + ((size_t)h * 2048 + pos) * 96 + d0) = v;
}

// ---------------- pack V^T tiled: qkv v-half -> Vp[h][kblk16][80][16] ----------------
__global__ __launch_bounds__(256) void pack_v_kernel(const unsigned short* __restrict__ qkv,
                                                     unsigned short* __restrict__ Vp) {
    int h  = blockIdx.x & 31;
    int g64 = blockIdx.x >> 5;           // 0..31
    int k0 = g64 * 64;
    int tid = threadIdx.x;
    for (int ci = tid; ci < 320; ci += 256) {   // (kbl 0..3) x (d 0..79)
        int d   = ci % 80;
        int kbl = ci / 80;
        unsigned short tmp[16];
        for (int j = 0; j < 16; ++j)
            tmp[j] = qkv[(size_t)(k0 + kbl * 16 + j) * 7680 + 5120 + h * 80 + d];
        unsigned short* dst = Vp + ((size_t)h * 128 + g64 * 4 + kbl) * 1280 + d * 16;
        *(s16x8*)dst       = *(const s16x8*)&tmp[0];
        *(s16x8*)(dst + 8) = *(const s16x8*)&tmp[8];
    }
}

// ---------------- flash attention v3: fixed-max softmax, split-K, pair-balanced ----------------
__global__ __launch_bounds__(256) void flash3_kernel(const unsigned short* __restrict__ qkv,
                                                     const unsigned short* __restrict__ Kp,
                                                     const unsigned short* __restrict__ Vp,
                                                     unsigned short* __restrict__ attn) {
    __shared__ unsigned short Pt[4][640];      // per-wave 16x40 P tile
    __shared__ float parts[2][16][84];         // odd-wave O partials (pitch 84)
    __shared__ float parts_l[2][16];           // odd-wave row-sum partials
    const int tid  = threadIdx.x;
    const int lane = tid & 63;
    const int wv   = tid >> 6;
    const int h = blockIdx.x & 31;
    const int p = blockIdx.x >> 5;             // 0..63
    const int s    = (wv < 2) ? p : (127 - p); // strip index (16 q rows)
    const int j    = wv & 1;                   // key-range half
    const int slot = wv >> 1;
    const int fr = lane & 15;
    const int fg = lane >> 4;
    const float k1 = 0.11180339887498949f * LOG2E;  // (1/sqrt(80)) * log2(e)
    const int sm16 = s * 16;

    const int n    = s + 1;                    // causal 16-key tiles
    const int half = (n + 1) >> 1;
    const int kstart = (j ? half : 0) * 16;
    const int kend   = (j ? n : half) * 16;

    s16x8 qf[3];
    {
        const unsigned short* qb = qkv + (size_t)(sm16 + fr) * 7680 + h * 80;
        const s16x8 zs = {0, 0, 0, 0, 0, 0, 0, 0};
        for (int sd = 0; sd < 3; ++sd) {
            int d = 32 * sd + fg * 8;
            qf[sd] = (d < 80) ? *(const s16x8*)(qb + d) : zs;
        }
    }

    f32x4 O[5];
    const f32x4 zf = {0.f, 0.f, 0.f, 0.f};
    for (int t = 0; t < 5; ++t) O[t] = zf;
    float rs[4] = {0.f, 0.f, 0.f, 0.f};

    const unsigned short* kptr = Kp + (size_t)h * 2048 * 96 + (size_t)(kstart + fr) * 96 + fg * 8;
    const unsigned short* vptr = Vp + (size_t)h * 128 * 1280 + (size_t)(kstart >> 4) * 1280
                                 + (fg >> 1) * 1280 + fr * 16 + (fg & 1) * 8;
    unsigned short* Pw = &Pt[wv][0];

    for (int k0 = kstart; k0 < kend; k0 += 32) {
        s16x8 kb[2][3];
        for (int g = 0; g < 2; ++g)
            for (int sd = 0; sd < 3; ++sd)
                kb[g][sd] = *(const s16x8*)(kptr + g * 1536 + sd * 32);
        s16x8 vb[5];
        for (int t = 0; t < 5; ++t)
            vb[t] = *(const s16x8*)(vptr + t * 256);

        f32x4 sa[2] = {zf, zf};
        for (int g = 0; g < 2; ++g)
            for (int sd = 0; sd < 3; ++sd)
                sa[g] = __builtin_amdgcn_mfma_f32_16x16x32_bf16(qf[sd], kb[g][sd], sa[g], 0, 0, 0);

        if (k0 + 32 > sm16 || k0 + 32 > kend) {
            for (int g = 0; g < 2; ++g)
                for (int r = 0; r < 4; ++r) {
                    int key  = k0 + g * 16 + fr;
                    int qrow = sm16 + fg * 4 + r;
                    if (key > qrow || key >= kend) sa[g][r] = -1e30f;
                }
        }

        float pr[2][4];
        for (int g = 0; g < 2; ++g)
            for (int r = 0; r < 4; ++r)
                pr[g][r] = __builtin_amdgcn_exp2f(sa[g][r] * k1);
        for (int r = 0; r < 4; ++r) rs[r] += pr[0][r] + pr[1][r];
        for (int g = 0; g < 2; ++g)
            for (int r = 0; r < 4; ++r)
                Pw[(fg * 4 + r) * 40 + g * 16 + fr] =
                    (unsigned short)(__float_as_uint(pr[g][r]) >> 16);

        s16x8 pa = *(const s16x8*)(Pw + fr * 40 + fg * 8);
        for (int t = 0; t < 5; ++t)
            O[t] = __builtin_amdgcn_mfma_f32_16x16x32_bf16(pa, vb[t], O[t], 0, 0, 0);

        kptr += 3072;   // 32 keys * 96
        vptr += 2560;   // 2 blocks * 1280
    }

    for (int r = 0; r < 4; ++r) {
        float v = rs[r];
        v += __shfl_xor(v, 1);
        v += __shfl_xor(v, 2);
        v += __shfl_xor(v, 4);
        v += __shfl_xor(v, 8);
        rs[r] = v;
    }

    if (j) {
        for (int t = 0; t < 5; ++t)
            for (int r = 0; r < 4; ++r)
                parts[slot][fg * 4 + r][t * 16 + fr] = O[t][r];
        if (fr == 0)
            for (int r = 0; r < 4; ++r) parts_l[slot][fg * 4 + r] = rs[r];
    }
    __syncthreads();
    if (!j) {
        for (int r = 0; r < 4; ++r) {
            float rl = 1.0f / (rs[r] + parts_l[slot][fg * 4 + r]);
            int row = sm16 + fg * 4 + r;
            for (int t = 0; t < 5; ++t) {
                float v = (O[t][r] + parts[slot][fg * 4 + r][t * 16 + fr]) * rl;
                attn[(size_t)row * 2560 + h * 80 + t * 16 + fr] = f2bf(v);
            }
        }
    }
}

extern "C" void kernel_launch(void* const* d_in, const int* in_sizes, int n_in,
                              void* d_out, int out_size, void* d_ws, size_t ws_size,
                              hipStream_t stream) {
    const float* x    = (const float*)d_in[0];
    const float* wqkv = (const float*)d_in[1];
    const float* bqkv = (const float*)d_in[2];
    const float* outw = (const float*)d_in[3];
    const float* outb = (const float*)d_in[4];

    unsigned short* xb    = (unsigned short*)d_ws;                  // 2048*2560
    unsigned short* wqkvb = xb + (size_t)2048 * 2560;               // 7680*2560 (dead after gemm1)
    unsigned short* Kp    = wqkvb;                                  // 32*2048*96   (aliases wqkvb)
    unsigned short* Vp    = wqkvb + (size_t)32 * 2048 * 96;         // 32*128*1280  (aliases wqkvb)
    unsigned short* outwb = wqkvb + (size_t)7680 * 2560;            // 2560*2560
    unsigned short* qkvb  = outwb + (size_t)2560 * 2560;            // 2048*7680
    unsigned short* attnb = qkvb  + (size_t)2048 * 7680;            // 2048*2560
    float* out = (float*)d_out;

    cast_bf16_kernel<<<2048 * 2560 / 4 / 256, 256, 0, stream>>>(x, xb, 2048 * 2560 / 4);
    cast_bf16_kernel<<<7680 * 2560 / 4 / 256, 256, 0, stream>>>(wqkv, wqkvb, 7680 * 2560 / 4);
    cast_bf16_kernel<<<2560 * 2560 / 4 / 256, 256, 0, stream>>>(outw, outwb, 2560 * 2560 / 4);

    // qkv projection: 256x256 v3 pipeline, 240 blocks, XCD-chunked panel-sharing map
    gemm256_bt<<<240, 512, 0, stream>>>(xb, wqkvb, bqkv, qkvb, 2048, 7680, 2560);

    rope_q_kernel<<<2048 * 64 / 256, 256, 0, stream>>>(qkvb);
    rope_pack_k_kernel<<<2048 * 384 / 256, 256, 0, stream>>>(qkvb, Kp);
    pack_v_kernel<<<32 * 32, 256, 0, stream>>>(qkvb, Vp);

    flash3_kernel<<<2048, 256, 0, stream>>>(qkvb, Kp, Vp, attnb);

    gemm_bt<false><<<dim3(2560 / 128, 2048 / 128), 256, 0, stream>>>(
        attnb, outwb, outb, (void*)out, 2048, 2560, 2560);
}